// Round 1
// baseline (4058.885 us; speedup 1.0000x reference)
//
#include <hip/hip_runtime.h>
#include <math.h>

// Problem constants (from reference setup_inputs)
#define NB 64      // batch
#define NS 128     // seq len
#define ND 128     // embed dim
#define NV 512     // vocab
#define NC 256     // hidden C
#define NN 256     // memory slots N
#define NM 64      // memory width M
#define NG 1024    // 4*C gate outputs
#define KIH 192    // D + M*H
#define KZ  320    // C + M*H
#define HST 208    // padded head output columns (198 used)
#define MPAD 65    // LDS mem row stride: (n*65+m)%32 = (n+m)%32 -> conflict-free

// Workspace layout (floats)
#define OFF_WIH  0
#define SZ_WIH   (KIH*NG)                 // 196608
#define OFF_WHH  (OFF_WIH + SZ_WIH)
#define SZ_WHH   (NC*NG)                  // 262144
#define OFF_OUTW (OFF_WHH + SZ_WHH)
#define SZ_OUTW  (KZ*NV)                  // 163840
#define OFF_HWT  (OFF_OUTW + SZ_OUTW)
#define SZ_HWT   (NC*HST)                 // 53248
#define OFF_BSUM (OFF_HWT + SZ_HWT)
#define OFF_HB   (OFF_BSUM + NG)
#define WS_FLOATS (OFF_HB + HST)          // 677072 floats = 2.71 MB

#define SMEM_FLOATS (NN*MPAD + NC + NC + NN + NN + NM + KIH + NG + HST + NN + NG + 32)
#define SMEM_BYTES  (SMEM_FLOATS * 4)     // 81856 bytes

__device__ __forceinline__ float sigf(float x) { return 1.0f / (1.0f + expf(-x)); }
__device__ __forceinline__ float splus(float x) { return (x > 20.f) ? x : log1pf(expf(x)); }

// ---------------- Preprocess: transpose weights into ws ----------------
__global__ void ntm_prep(const float* __restrict__ W_ih, const float* __restrict__ W_hh,
                         const float* __restrict__ b_ih, const float* __restrict__ b_hh,
                         const float* __restrict__ key_W, const float* __restrict__ key_b,
                         const float* __restrict__ beta_W, const float* __restrict__ beta_b,
                         const float* __restrict__ gate_W, const float* __restrict__ gate_b,
                         const float* __restrict__ shift_W, const float* __restrict__ shift_b,
                         const float* __restrict__ gamma_W, const float* __restrict__ gamma_b,
                         const float* __restrict__ erase_W, const float* __restrict__ erase_b,
                         const float* __restrict__ add_W, const float* __restrict__ add_b,
                         const float* __restrict__ out_W, float* __restrict__ ws)
{
  for (int idx = blockIdx.x * blockDim.x + threadIdx.x; idx < WS_FLOATS;
       idx += gridDim.x * blockDim.x) {
    float v;
    if (idx < OFF_WHH) {                       // WihT[k][o] = W_ih[o][k]
      int i = idx, k = i / NG, o = i % NG;
      v = W_ih[o * KIH + k];
    } else if (idx < OFF_OUTW) {               // WhhT[k][o] = W_hh[o][k]
      int i = idx - OFF_WHH, k = i / NG, o = i % NG;
      v = W_hh[o * NC + k];
    } else if (idx < OFF_HWT) {                // outWT[k][o] = out_W[o][k]
      int i = idx - OFF_OUTW, k = i / NV, o = i % NV;
      v = out_W[o * KZ + k];
    } else if (idx < OFF_BSUM) {               // packed head weights, transposed
      int i = idx - OFF_HWT, k = i / HST, c = i % HST;
      if (c < 64)       v = key_W[c * NC + k];
      else if (c < 128) v = erase_W[(c - 64) * NC + k];
      else if (c < 192) v = add_W[(c - 128) * NC + k];
      else if (c < 195) v = shift_W[(c - 192) * NC + k];
      else if (c == 195) v = beta_W[k];
      else if (c == 196) v = gate_W[k];
      else if (c == 197) v = gamma_W[k];
      else v = 0.0f;
    } else if (idx < OFF_HB) {                 // bsum = b_ih + b_hh
      int o = idx - OFF_BSUM;
      v = b_ih[o] + b_hh[o];
    } else {                                   // packed head biases
      int c = idx - OFF_HB;
      if (c < 64)       v = key_b[c];
      else if (c < 128) v = erase_b[c - 64];
      else if (c < 192) v = add_b[c - 128];
      else if (c < 195) v = shift_b[c - 192];
      else if (c == 195) v = beta_b[0];
      else if (c == 196) v = gate_b[0];
      else if (c == 197) v = gamma_b[0];
      else v = 0.0f;
    }
    ws[idx] = v;
  }
}

// ---------------- Main: one block per batch element, full scan ----------------
__launch_bounds__(1024, 1)
__global__ void ntm_main(const int* __restrict__ x, const float* __restrict__ emb,
                         const float* __restrict__ out_b, const float* __restrict__ mem_init,
                         const float* __restrict__ ws, float* __restrict__ out)
{
  const int b = blockIdx.x;
  const int tid = threadIdx.x;
  const float* WihT  = ws + OFF_WIH;
  const float* WhhT  = ws + OFF_WHH;
  const float* outWT = ws + OFF_OUTW;
  const float* HWT   = ws + OFF_HWT;
  const float* bsum  = ws + OFF_BSUM;
  const float* hb    = ws + OFF_HB;

  extern __shared__ float sm[];
  float* s_mem = sm;                    // NN*MPAD
  float* s_h   = s_mem + NN * MPAD;     // NC
  float* s_c   = s_h + NC;              // NC
  float* s_rw  = s_c + NC;              // NN
  float* s_w   = s_rw + NN;             // NN
  float* s_rv  = s_w + NN;              // NM
  float* s_ci  = s_rv + NM;             // KIH
  float* s_g   = s_ci + KIH;            // NG
  float* s_hd  = s_g + NG;              // HST
  float* s_sim = s_hd + HST;            // NN
  float* s_tmp = s_sim + NN;            // NG
  float* s_red = s_tmp + NG;            // 32

  // init state
  for (int i = tid; i < NN * NM; i += 1024) {
    int n = i >> 6, m = i & 63;
    s_mem[n * MPAD + m] = mem_init[b * NN * NM + i];
  }
  if (tid < NC) { s_h[tid] = 0.f; s_c[tid] = 0.f; }
  if (tid < NN) s_rw[tid] = 0.f;
  if (tid < NM) s_rv[tid] = 0.f;
  __syncthreads();

  for (int t = 0; t < NS; ++t) {
    // 1. ci = [emb[x_t], rv]
    int tok = x[b * NS + t];
    if (tid < ND)       s_ci[tid] = emb[tok * ND + tid];
    else if (tid < KIH) s_ci[tid] = s_rv[tid - ND];
    __syncthreads();

    // 2. gates[o] = bsum[o] + ci.WihT + h.WhhT   (one output per thread)
    {
      float acc = bsum[tid];
      const float* wp = WihT + tid;
      #pragma unroll 8
      for (int k = 0; k < KIH; ++k) acc = fmaf(wp[k * NG], s_ci[k], acc);
      const float* wp2 = WhhT + tid;
      #pragma unroll 8
      for (int k = 0; k < NC; ++k) acc = fmaf(wp2[k * NG], s_h[k], acc);
      s_g[tid] = acc;
    }
    __syncthreads();

    // 3. LSTM cell update (torch gate order i,f,g,o)
    if (tid < NC) {
      float ig = sigf(s_g[tid]);
      float fg = sigf(s_g[NC + tid]);
      float gg = tanhf(s_g[2 * NC + tid]);
      float og = sigf(s_g[3 * NC + tid]);
      float cn = fg * s_c[tid] + ig * gg;
      s_c[tid] = cn;
      s_h[tid] = og * tanhf(cn);
    }
    __syncthreads();

    // 4. head linears: 208 cols x 4 k-chunks of 64
    if (tid < 4 * HST) {
      int col = tid % HST, q = tid / HST;
      const float* wp = HWT + col;
      float acc = 0.f;
      int k0 = q * 64;
      #pragma unroll 8
      for (int kk = 0; kk < 64; ++kk) acc = fmaf(wp[(k0 + kk) * HST], s_h[k0 + kk], acc);
      s_tmp[q * HST + col] = acc;
    }
    __syncthreads();
    if (tid < HST)
      s_hd[tid] = hb[tid] + s_tmp[tid] + s_tmp[HST + tid] + s_tmp[2 * HST + tid] + s_tmp[3 * HST + tid];
    __syncthreads();

    // 5. activations: keyN (cols 0..63), erase sig (64..127), add tanh (128..191),
    //    shift softmax (192..194), beta softplus (195), gate sig (196), gamma 1+softplus (197)
    if (tid < 64) {
      float kv = s_hd[tid];
      float ss = kv * kv;
      for (int off = 32; off >= 1; off >>= 1) ss += __shfl_xor(ss, off);
      float kn = fmaxf(sqrtf(ss), 1e-12f);
      s_hd[tid] = kv / kn;
    } else if (tid < 128) {
      s_hd[tid] = sigf(s_hd[tid]);
    } else if (tid < 192) {
      s_hd[tid] = tanhf(s_hd[tid]);
    } else if (tid == 192) {
      float a = s_hd[192], bb = s_hd[193], cc = s_hd[194];
      float mx = fmaxf(a, fmaxf(bb, cc));
      float e0 = expf(a - mx), e1 = expf(bb - mx), e2 = expf(cc - mx);
      float s = e0 + e1 + e2;
      s_hd[192] = e0 / s; s_hd[193] = e1 / s; s_hd[194] = e2 / s;
    } else if (tid == 195) {
      s_hd[195] = splus(s_hd[195]);
    } else if (tid == 196) {
      s_hd[196] = sigf(s_hd[196]);
    } else if (tid == 197) {
      s_hd[197] = 1.0f + splus(s_hd[197]);
    }
    __syncthreads();

    // 6. cosine sim: sim[n] = dot(mem[n],keyN)/max(||mem[n]||,eps)   (4 lanes per n)
    {
      int n = tid >> 2, q = tid & 3;
      const float* mrow = s_mem + n * MPAD + q * 16;
      float dot = 0.f, sq = 0.f;
      #pragma unroll
      for (int i = 0; i < 16; ++i) {
        float mv = mrow[i];
        dot = fmaf(mv, s_hd[q * 16 + i], dot);
        sq  = fmaf(mv, mv, sq);
      }
      dot += __shfl_xor(dot, 1); dot += __shfl_xor(dot, 2);
      sq  += __shfl_xor(sq, 1);  sq  += __shfl_xor(sq, 2);
      if (q == 0) {
        float rn = fmaxf(sqrtf(sq), 1e-12f);
        s_sim[n] = dot / rn;
      }
    }
    __syncthreads();

    // 7. w_c = softmax(beta*sim); w_g = gate*w_c+(1-gate)*rw; shift-conv; sharpen
    float beta = s_hd[195], gate = s_hd[196], gamma = s_hd[197];
    float sh0 = s_hd[192], sh1 = s_hd[193], sh2 = s_hd[194];
    {
      float v = (tid < NN) ? beta * s_sim[tid] : -1e30f;
      float m_ = v;
      for (int off = 32; off >= 1; off >>= 1) m_ = fmaxf(m_, __shfl_xor(m_, off));
      if (tid < NN && (tid & 63) == 0) s_red[tid >> 6] = m_;
      __syncthreads();
      float gmax = fmaxf(fmaxf(s_red[0], s_red[1]), fmaxf(s_red[2], s_red[3]));
      float e = (tid < NN) ? expf(v - gmax) : 0.f;
      float s_ = e;
      for (int off = 32; off >= 1; off >>= 1) s_ += __shfl_xor(s_, off);
      if (tid < NN && (tid & 63) == 0) s_red[4 + (tid >> 6)] = s_;
      __syncthreads();
      float gsum = s_red[4] + s_red[5] + s_red[6] + s_red[7];
      if (tid < NN) {
        float wc = e / gsum;
        s_tmp[tid] = gate * wc + (1.f - gate) * s_rw[tid];  // w_g
      }
    }
    __syncthreads();
    if (tid < NN) {
      // w_[i] = sh0*w_g[i+1] + sh1*w_g[i] + sh2*w_g[i-1]  (circular, from jnp.roll)
      float wg = sh0 * s_tmp[(tid + 1) & (NN - 1)] + sh1 * s_tmp[tid]
               + sh2 * s_tmp[(tid + NN - 1) & (NN - 1)];
      s_sim[tid] = powf(wg, gamma);
    }
    __syncthreads();
    {
      float v = (tid < NN) ? s_sim[tid] : 0.f;
      float s_ = v;
      for (int off = 32; off >= 1; off >>= 1) s_ += __shfl_xor(s_, off);
      if (tid < NN && (tid & 63) == 0) s_red[8 + (tid >> 6)] = s_;
      __syncthreads();
      float psum = s_red[8] + s_red[9] + s_red[10] + s_red[11];
      if (tid < NN) {
        float wv = v / psum;
        s_w[tid] = wv;
        s_rw[tid] = wv;  // carry for next step
      }
    }
    __syncthreads();

    // 8. rv = w @ mem  (pre-update mem); 16 n-chunks x 64 m
    {
      int m = tid & 63, q = tid >> 6;
      float acc = 0.f;
      int n0 = q * 16;
      #pragma unroll
      for (int i = 0; i < 16; ++i) {
        int n = n0 + i;
        acc = fmaf(s_w[n], s_mem[n * MPAD + m], acc);
      }
      s_tmp[q * 64 + m] = acc;
    }
    __syncthreads();
    if (tid < NM) {
      float acc = 0.f;
      #pragma unroll
      for (int q = 0; q < 16; ++q) acc += s_tmp[q * 64 + tid];
      s_rv[tid] = acc;
    }
    // 9. mem = mem*(1 - w*er) + w*ad   (safe: sync above ordered all phase-8 reads)
    for (int i = tid; i < NN * NM; i += 1024) {
      int n = i >> 6, m = i & 63;
      float wv = s_w[n];
      float cur = s_mem[n * MPAD + m];
      s_mem[n * MPAD + m] = cur * (1.f - wv * s_hd[64 + m]) + wv * s_hd[128 + m];
    }
    __syncthreads();

    // 10. logits = [h, rv] @ outWT + out_b
    {
      int o = tid & 511, half = tid >> 9;
      const float* wp = outWT + o;
      float acc = 0.f;
      int k0 = half * 160;
      #pragma unroll 4
      for (int kk = 0; kk < 160; ++kk) {
        int k = k0 + kk;
        float z = (k < NC) ? s_h[k] : s_rv[k - NC];
        acc = fmaf(wp[k * NV], z, acc);
      }
      s_tmp[half * NV + o] = acc;
    }
    __syncthreads();
    if (tid < NV)
      out[((b * NS + t) * NV) + tid] = out_b[tid] + s_tmp[tid] + s_tmp[NV + tid];
    __syncthreads();
  }
}

extern "C" void kernel_launch(void* const* d_in, const int* in_sizes, int n_in,
                              void* d_out, int out_size, void* d_ws, size_t ws_size,
                              hipStream_t stream) {
  const int*   x       = (const int*)  d_in[0];
  const float* emb     = (const float*)d_in[1];
  const float* W_ih    = (const float*)d_in[2];
  const float* W_hh    = (const float*)d_in[3];
  const float* b_ih    = (const float*)d_in[4];
  const float* b_hh    = (const float*)d_in[5];
  const float* key_W   = (const float*)d_in[6];
  const float* key_b   = (const float*)d_in[7];
  const float* beta_W  = (const float*)d_in[8];
  const float* beta_b  = (const float*)d_in[9];
  const float* gate_W  = (const float*)d_in[10];
  const float* gate_b  = (const float*)d_in[11];
  const float* shift_W = (const float*)d_in[12];
  const float* shift_b = (const float*)d_in[13];
  const float* gamma_W = (const float*)d_in[14];
  const float* gamma_b = (const float*)d_in[15];
  const float* erase_W = (const float*)d_in[16];
  const float* erase_b = (const float*)d_in[17];
  const float* add_W   = (const float*)d_in[18];
  const float* add_b   = (const float*)d_in[19];
  const float* out_W   = (const float*)d_in[20];
  const float* out_b   = (const float*)d_in[21];
  const float* mem_init= (const float*)d_in[22];
  float* ws  = (float*)d_ws;
  float* out = (float*)d_out;

  int prep_blocks = (WS_FLOATS + 255) / 256;
  ntm_prep<<<prep_blocks, 256, 0, stream>>>(W_ih, W_hh, b_ih, b_hh, key_W, key_b,
      beta_W, beta_b, gate_W, gate_b, shift_W, shift_b, gamma_W, gamma_b,
      erase_W, erase_b, add_W, add_b, out_W, ws);

  // 80KB dynamic LDS (>64KB default cap; gfx950 has 160KB/CU) — idempotent, every call
  hipFuncSetAttribute((const void*)ntm_main, hipFuncAttributeMaxDynamicSharedMemorySize,
                      SMEM_BYTES);
  ntm_main<<<NB, 1024, SMEM_BYTES, stream>>>(x, emb, out_b, mem_init, ws, out);
}

// Round 3
// 3414.634 us; speedup vs baseline: 1.1887x; 1.1887x over previous
//
#include <hip/hip_runtime.h>
#include <hip/hip_fp16.h>
#include <math.h>

// Problem constants
#define NB 64
#define NS 128
#define ND 128
#define NV 512
#define NC 256
#define NN 256
#define NM 64
#define NG 1024
#define KIH 192
#define KZ  320
#define HST 208
#define MPAD 65

// ws layout: fp16 weights packed as uint2 (4 halves each), then fp32 biases, then hrv
#define U2_WIH 0          // [KIH][NG] -> 192*256 uint2
#define U2_WHH 49152      // [NC][NG]  -> 256*256
#define U2_HWT 114688     // [NC][208] -> 256*52
#define U2_OUT 128000     // [KZ][NV]  -> 320*128
#define U2_END 168960
#define F_BSUM 337920     // 1024 floats (= U2_END*2)
#define F_HB   338944     // 208 floats (pad to 256)
#define F_HRV  339200     // 8192*320 floats
#define WS_SPLIT_BYTES 11842560u
#define PREP_ITEMS (U2_END + NG + HST)

// LDS layout (floats)
#define L_MEM 0
#define L_H   (NN*MPAD)          // 16640
#define L_C   (L_H + NC)
#define L_RW  (L_C + NC)
#define L_W   (L_RW + NN)
#define L_RV  (L_W + NN)
#define L_CI  (L_RV + NM)
#define L_HD  (L_CI + KIH)
#define L_SIM (L_HD + HST)
#define L_PART (L_SIM + NN)      // 16B aligned
#define SMEM_FLOATS (L_PART + 4096)
#define SMEM_BYTES (SMEM_FLOATS * 4)   // 89920 B

__device__ __forceinline__ float sigf(float x) { return 1.0f / (1.0f + expf(-x)); }
__device__ __forceinline__ float splus(float x) { return (x > 20.f) ? x : log1pf(expf(x)); }

// fp16 unpack: low/high half of a uint
__device__ __forceinline__ float hlo(unsigned u) {
  unsigned short s = (unsigned short)(u & 0xffffu);
  _Float16 h;
  __builtin_memcpy(&h, &s, 2);
  return (float)h;
}
__device__ __forceinline__ float hhi(unsigned u) {
  unsigned short s = (unsigned short)(u >> 16);
  _Float16 h;
  __builtin_memcpy(&h, &s, 2);
  return (float)h;
}
__device__ __forceinline__ unsigned short f2h(float f) {  // RNE
  _Float16 h = (_Float16)f;
  unsigned short s;
  __builtin_memcpy(&s, &h, 2);
  return s;
}

__device__ float head_w(int c, int k, const float* kW, const float* eW, const float* aW,
                        const float* sW, const float* bW, const float* gW, const float* gaW) {
  if (c < 64)  return kW[c * NC + k];
  if (c < 128) return eW[(c - 64) * NC + k];
  if (c < 192) return aW[(c - 128) * NC + k];
  if (c < 195) return sW[(c - 192) * NC + k];
  if (c == 195) return bW[k];
  if (c == 196) return gW[k];
  if (c == 197) return gaW[k];
  return 0.0f;
}

// ---------------- Preprocess: transpose + fp16-pack weights into ws ----------------
__global__ void ntm_prep(const float* __restrict__ W_ih, const float* __restrict__ W_hh,
                         const float* __restrict__ b_ih, const float* __restrict__ b_hh,
                         const float* __restrict__ key_W, const float* __restrict__ key_b,
                         const float* __restrict__ beta_W, const float* __restrict__ beta_b,
                         const float* __restrict__ gate_W, const float* __restrict__ gate_b,
                         const float* __restrict__ shift_W, const float* __restrict__ shift_b,
                         const float* __restrict__ gamma_W, const float* __restrict__ gamma_b,
                         const float* __restrict__ erase_W, const float* __restrict__ erase_b,
                         const float* __restrict__ add_W, const float* __restrict__ add_b,
                         const float* __restrict__ out_W, float* __restrict__ ws)
{
  uint2* w4 = (uint2*)ws;
  for (int idx = blockIdx.x * blockDim.x + threadIdx.x; idx < PREP_ITEMS;
       idx += gridDim.x * blockDim.x) {
    if (idx < U2_END) {
      float v[4];
      if (idx < U2_WHH) {
        int k = idx >> 8, og = idx & 255;
        #pragma unroll
        for (int j = 0; j < 4; ++j) v[j] = W_ih[(og * 4 + j) * KIH + k];
      } else if (idx < U2_HWT) {
        int i = idx - U2_WHH, k = i >> 8, og = i & 255;
        #pragma unroll
        for (int j = 0; j < 4; ++j) v[j] = W_hh[(og * 4 + j) * NC + k];
      } else if (idx < U2_OUT) {
        int i = idx - U2_HWT, k = i / 52, cq = i % 52;
        #pragma unroll
        for (int j = 0; j < 4; ++j)
          v[j] = head_w(cq * 4 + j, k, key_W, erase_W, add_W, shift_W, beta_W, gate_W, gamma_W);
      } else {
        int i = idx - U2_OUT, k = i >> 7, og = i & 127;
        #pragma unroll
        for (int j = 0; j < 4; ++j) v[j] = out_W[(og * 4 + j) * KZ + k];
      }
      uint2 p;
      p.x = (unsigned)f2h(v[0]) | ((unsigned)f2h(v[1]) << 16);
      p.y = (unsigned)f2h(v[2]) | ((unsigned)f2h(v[3]) << 16);
      w4[idx] = p;
    } else if (idx < U2_END + NG) {
      int o = idx - U2_END;
      ws[F_BSUM + o] = b_ih[o] + b_hh[o];
    } else {
      int c = idx - U2_END - NG;
      float v;
      if (c < 64)       v = key_b[c];
      else if (c < 128) v = erase_b[c - 64];
      else if (c < 192) v = add_b[c - 128];
      else if (c < 195) v = shift_b[c - 192];
      else if (c == 195) v = beta_b[0];
      else if (c == 196) v = gate_b[0];
      else               v = gamma_b[0];   // c == 197
      ws[F_HB + c] = v;
    }
  }
}

// ---------------- Main: one block per batch element, full scan ----------------
template <int SPLIT>
__launch_bounds__(1024, 1)
__global__ void ntm_main(const int* __restrict__ x, const float* __restrict__ emb,
                         const float* __restrict__ out_b, const float* __restrict__ mem_init,
                         const float* __restrict__ ws, float* __restrict__ out)
{
  const int b = blockIdx.x;
  const int tid = threadIdx.x;
  const uint2* WIH4 = (const uint2*)ws;
  const uint2* WHH4 = WIH4 + U2_WHH;
  const uint2* HWT4 = WIH4 + U2_HWT;
  const uint2* OUT4 = WIH4 + U2_OUT;
  const float* bsum = ws + F_BSUM;
  const float* hb   = ws + F_HB;
  float* hrv = (float*)(ws + F_HRV);

  extern __shared__ float sm[];
  float* s_mem = sm + L_MEM;
  float* s_h   = sm + L_H;
  float* s_c   = sm + L_C;
  float* s_rw  = sm + L_RW;
  float* s_w   = sm + L_W;
  float* s_rv  = sm + L_RV;
  float* s_ci  = sm + L_CI;
  float* s_hd  = sm + L_HD;
  float* s_sim = sm + L_SIM;
  float* s_part = sm + L_PART;
  float4* s_part4 = (float4*)s_part;

  // per-thread constant mappings
  const int og2 = tid & 255, q2 = tid >> 8;          // phase 2
  const int p4cq = tid % 52, p4q = tid / 52;         // phase 4 (tid<416)
  const int n6 = tid >> 2, q6 = tid & 3;             // phase 6
  const int m8 = tid & 63, q8 = tid >> 6;            // phase 8

  // init state
  for (int i = tid; i < NN * NM; i += 1024) {
    int n = i >> 6, m = i & 63;
    s_mem[n * MPAD + m] = mem_init[b * NN * NM + i];
  }
  if (tid < NC) { s_h[tid] = 0.f; s_c[tid] = 0.f; }
  if (tid < NN) s_rw[tid] = 0.f;
  if (tid < NM) s_rv[tid] = 0.f;
  __syncthreads();

  for (int t = 0; t < NS; ++t) {
    // ---- phase A: ci = [emb, rv]; store hrv of step t-1 (SPLIT) ----
    {
      int tok = x[b * NS + t];
      if (tid < KIH) s_ci[tid] = (tid < ND) ? emb[tok * ND + tid] : s_rv[tid - ND];
      if (SPLIT && t > 0 && tid >= 192 && tid < 512) {
        int i = tid - 192;
        hrv[(size_t)(b * NS + (t - 1)) * KZ + i] = (i < NC) ? s_h[i] : s_rv[i - NC];
      }
    }
    __syncthreads();  // S1

    // ---- phase 2: gate partials, 4 outputs x 4 k-chunks per thread ----
    {
      float4 acc = {0.f, 0.f, 0.f, 0.f};
      const uint2* pih = WIH4 + (q2 * 48) * 256 + og2;
      const float* cip = s_ci + q2 * 48;
      #pragma unroll 8
      for (int kk = 0; kk < 48; ++kk) {
        uint2 w = pih[kk * 256];
        float a = cip[kk];
        acc.x = fmaf(hlo(w.x), a, acc.x); acc.y = fmaf(hhi(w.x), a, acc.y);
        acc.z = fmaf(hlo(w.y), a, acc.z); acc.w = fmaf(hhi(w.y), a, acc.w);
      }
      const uint2* phh = WHH4 + (q2 * 64) * 256 + og2;
      const float* hp = s_h + q2 * 64;
      #pragma unroll 8
      for (int kk = 0; kk < 64; ++kk) {
        uint2 w = phh[kk * 256];
        float a = hp[kk];
        acc.x = fmaf(hlo(w.x), a, acc.x); acc.y = fmaf(hhi(w.x), a, acc.y);
        acc.z = fmaf(hlo(w.y), a, acc.z); acc.w = fmaf(hhi(w.y), a, acc.w);
      }
      s_part4[q2 * 256 + og2] = acc;
    }
    __syncthreads();  // S2

    // ---- phase 3': combine gates + LSTM cell (torch order i,f,g,o) ----
    if (tid < NC) {
      float gi = bsum[tid], gf = bsum[NC + tid], gg = bsum[2 * NC + tid], go = bsum[3 * NC + tid];
      #pragma unroll
      for (int q = 0; q < 4; ++q) {
        const float* pp = s_part + q * NG;
        gi += pp[tid]; gf += pp[NC + tid]; gg += pp[2 * NC + tid]; go += pp[3 * NC + tid];
      }
      float cn = sigf(gf) * s_c[tid] + sigf(gi) * tanhf(gg);
      s_c[tid] = cn;
      s_h[tid] = sigf(go) * tanhf(cn);
    }
    __syncthreads();  // S3

    // ---- phase 4: head-linear partials (52 col-quads x 8 k-chunks of 32) ----
    if (tid < 416) {
      float4 acc = {0.f, 0.f, 0.f, 0.f};
      const uint2* ph = HWT4 + (p4q * 32) * 52 + p4cq;
      const float* hp = s_h + p4q * 32;
      #pragma unroll 8
      for (int kk = 0; kk < 32; ++kk) {
        uint2 w = ph[kk * 52];
        float a = hp[kk];
        acc.x = fmaf(hlo(w.x), a, acc.x); acc.y = fmaf(hhi(w.x), a, acc.y);
        acc.z = fmaf(hlo(w.y), a, acc.z); acc.w = fmaf(hhi(w.y), a, acc.w);
      }
      s_part4[p4q * 52 + p4cq] = acc;
    }
    __syncthreads();  // S4

    // ---- phase 5: combine + activations (wave-aligned) ----
    if (tid < 256) {
      float val = 0.f;
      if (tid < HST) {
        val = hb[tid];
        #pragma unroll
        for (int q = 0; q < 8; ++q) val += s_part[q * HST + tid];
      }
      int wv = tid >> 6;
      if (wv == 0) {            // key l2-normalize
        float ss = val * val;
        for (int off = 32; off; off >>= 1) ss += __shfl_xor(ss, off);
        s_hd[tid] = val / fmaxf(sqrtf(ss), 1e-12f);
      } else if (wv == 1) {     // erase: sigmoid
        s_hd[tid] = sigf(val);
      } else if (wv == 2) {     // add: tanh
        s_hd[tid] = tanhf(val);
      } else {                  // wave 3: shift softmax + scalars
        int l = tid & 63;
        float a0 = __shfl(val, 0), a1 = __shfl(val, 1), a2 = __shfl(val, 2);
        float mx = fmaxf(a0, fmaxf(a1, a2));
        float e0 = expf(a0 - mx), e1 = expf(a1 - mx), e2 = expf(a2 - mx);
        float ss = e0 + e1 + e2;
        float r = 0.f;
        if (l == 0) r = e0 / ss;
        else if (l == 1) r = e1 / ss;
        else if (l == 2) r = e2 / ss;
        else if (l == 3) r = splus(val);          // beta  (col 195)
        else if (l == 4) r = sigf(val);           // gate  (col 196)
        else if (l == 5) r = 1.0f + splus(val);   // gamma (col 197)
        if (l < 16) s_hd[192 + l] = r;
      }
    }
    __syncthreads();  // S5

    // ---- phase 6: cosine sim (4 lanes per memory row) ----
    {
      const float* mrow = s_mem + n6 * MPAD + q6 * 16;
      const float* kp = s_hd + q6 * 16;
      float dot = 0.f, sq = 0.f;
      #pragma unroll
      for (int i = 0; i < 16; ++i) {
        float mv = mrow[i];
        dot = fmaf(mv, kp[i], dot);
        sq  = fmaf(mv, mv, sq);
      }
      dot += __shfl_xor(dot, 1); dot += __shfl_xor(dot, 2);
      sq  += __shfl_xor(sq, 1);  sq  += __shfl_xor(sq, 2);
      if (q6 == 0) s_sim[n6] = dot / fmaxf(sqrtf(sq), 1e-12f);
    }
    __syncthreads();  // S6

    // ---- phase 7: full addressing chain in one wave (4 slots/lane) ----
    if (tid < 64) {
      int l = tid;
      float beta = s_hd[195], gate = s_hd[196], gamma = s_hd[197];
      float sh0 = s_hd[192], sh1 = s_hd[193], sh2 = s_hd[194];
      float v0 = beta * s_sim[l], v1 = beta * s_sim[64 + l];
      float v2 = beta * s_sim[128 + l], v3 = beta * s_sim[192 + l];
      float mx = fmaxf(fmaxf(v0, v1), fmaxf(v2, v3));
      for (int off = 32; off; off >>= 1) mx = fmaxf(mx, __shfl_xor(mx, off));
      float e0 = expf(v0 - mx), e1 = expf(v1 - mx), e2 = expf(v2 - mx), e3 = expf(v3 - mx);
      float s = e0 + e1 + e2 + e3;
      for (int off = 32; off; off >>= 1) s += __shfl_xor(s, off);
      float inv = 1.0f / s, omg = 1.0f - gate;
      float wg[4];
      wg[0] = gate * e0 * inv + omg * s_rw[l];
      wg[1] = gate * e1 * inv + omg * s_rw[64 + l];
      wg[2] = gate * e2 * inv + omg * s_rw[128 + l];
      wg[3] = gate * e3 * inv + omg * s_rw[192 + l];
      float p[4]; float ps = 0.f;
      #pragma unroll
      for (int j = 0; j < 4; ++j) {
        float cu = (l == 0) ? wg[(j + 1) & 3] : wg[j];
        float up = __shfl(cu, (l + 1) & 63);
        float cd = (l == 63) ? wg[(j + 3) & 3] : wg[j];
        float dn = __shfl(cd, (l + 63) & 63);
        float wn = fmaf(sh0, up, fmaf(sh1, wg[j], sh2 * dn));
        p[j] = powf(wn, gamma);
        ps += p[j];
      }
      for (int off = 32; off; off >>= 1) ps += __shfl_xor(ps, off);
      float invp = 1.0f / ps;
      #pragma unroll
      for (int j = 0; j < 4; ++j) {
        float wv = p[j] * invp;
        s_w[l + 64 * j] = wv;
        s_rw[l + 64 * j] = wv;
      }
    }
    __syncthreads();  // S7

    // ---- phase 8: rv partials = w @ mem (16 n-chunks x 64 m) ----
    {
      float acc = 0.f;
      int n0 = q8 * 16;
      #pragma unroll
      for (int i = 0; i < 16; ++i) {
        int n = n0 + i;
        acc = fmaf(s_w[n], s_mem[n * MPAD + m8], acc);
      }
      s_part[q8 * 64 + m8] = acc;
    }
    __syncthreads();  // S8

    // ---- phase 9: rv combine + memory update ----
    if (tid < NM) {
      float acc = 0.f;
      #pragma unroll
      for (int q = 0; q < 16; ++q) acc += s_part[q * 64 + tid];
      s_rv[tid] = acc;
    }
    for (int i = tid; i < NN * NM; i += 1024) {
      int n = i >> 6, m = i & 63;
      float wv = s_w[n];
      float cur = s_mem[n * MPAD + m];
      s_mem[n * MPAD + m] = cur * (1.f - wv * s_hd[64 + m]) + wv * s_hd[128 + m];
    }
    __syncthreads();  // S9

    if (!SPLIT) {
      // fused logits: 4 cols x 8 k-chunks of 40 per thread
      {
        int ogo = tid & 127, qo = tid >> 7;
        const uint2* pw = OUT4 + (qo * 40) * 128 + ogo;
        float4 acc = {0.f, 0.f, 0.f, 0.f};
        #pragma unroll 8
        for (int kk = 0; kk < 40; ++kk) {
          int k = qo * 40 + kk;
          float a = (k < NC) ? s_h[k] : s_rv[k - NC];
          uint2 w = pw[kk * 128];
          acc.x = fmaf(hlo(w.x), a, acc.x); acc.y = fmaf(hhi(w.x), a, acc.y);
          acc.z = fmaf(hlo(w.y), a, acc.z); acc.w = fmaf(hhi(w.y), a, acc.w);
        }
        s_part4[qo * 128 + ogo] = acc;
      }
      __syncthreads();
      if (tid < NV) {
        float r = out_b[tid];
        #pragma unroll
        for (int q = 0; q < 8; ++q) r += s_part[q * NV + tid];
        out[((size_t)(b * NS + t)) * NV + tid] = r;
      }
      __syncthreads();
    }
  }

  if (SPLIT && tid >= 192 && tid < 512) {
    int i = tid - 192;
    hrv[(size_t)(b * NS + NS - 1) * KZ + i] = (i < NC) ? s_h[i] : s_rv[i - NC];
  }
}

// ---------------- Logits GEMM: 8192 x 512, K=320, fp16 weights ----------------
__launch_bounds__(512)
__global__ void ntm_logits(const float* __restrict__ ws, const float* __restrict__ out_b,
                           float* __restrict__ out)
{
  const uint2* OUT4 = ((const uint2*)ws) + U2_OUT;
  const float* hrv = ws + F_HRV;
  __shared__ float s_z[16 * 321];
  const int tid = threadIdx.x;
  const int r0 = blockIdx.x * 16;
  {
    int r = tid >> 5, i0 = tid & 31;
    const float* src = hrv + (size_t)(r0 + r) * KZ;
    for (int i = i0; i < KZ; i += 32) s_z[r * 321 + i] = src[i];
  }
  __syncthreads();
  const int og = tid & 127, rq = tid >> 7;
  const int rb = rq * 4;
  const uint2* pw = OUT4 + og;
  float4 a0 = {0,0,0,0}, a1 = a0, a2 = a0, a3 = a0;
  #pragma unroll 4
  for (int k = 0; k < KZ; ++k) {
    uint2 w = pw[k * 128];
    float w0 = hlo(w.x), w1 = hhi(w.x), w2 = hlo(w.y), w3 = hhi(w.y);
    float z0 = s_z[(rb + 0) * 321 + k], z1 = s_z[(rb + 1) * 321 + k];
    float z2 = s_z[(rb + 2) * 321 + k], z3 = s_z[(rb + 3) * 321 + k];
    a0.x = fmaf(w0, z0, a0.x); a0.y = fmaf(w1, z0, a0.y); a0.z = fmaf(w2, z0, a0.z); a0.w = fmaf(w3, z0, a0.w);
    a1.x = fmaf(w0, z1, a1.x); a1.y = fmaf(w1, z1, a1.y); a1.z = fmaf(w2, z1, a1.z); a1.w = fmaf(w3, z1, a1.w);
    a2.x = fmaf(w0, z2, a2.x); a2.y = fmaf(w1, z2, a2.y); a2.z = fmaf(w2, z2, a2.z); a2.w = fmaf(w3, z2, a2.w);
    a3.x = fmaf(w0, z3, a3.x); a3.y = fmaf(w1, z3, a3.y); a3.z = fmaf(w2, z3, a3.z); a3.w = fmaf(w3, z3, a3.w);
  }
  float4 ob = *(const float4*)(out_b + og * 4);
  a0.x += ob.x; a0.y += ob.y; a0.z += ob.z; a0.w += ob.w;
  a1.x += ob.x; a1.y += ob.y; a1.z += ob.z; a1.w += ob.w;
  a2.x += ob.x; a2.y += ob.y; a2.z += ob.z; a2.w += ob.w;
  a3.x += ob.x; a3.y += ob.y; a3.z += ob.z; a3.w += ob.w;
  float4* po = (float4*)(out + (size_t)(r0 + rb) * NV + og * 4);
  po[0 * (NV / 4)] = a0;
  po[1 * (NV / 4)] = a1;
  po[2 * (NV / 4)] = a2;
  po[3 * (NV / 4)] = a3;
}

extern "C" void kernel_launch(void* const* d_in, const int* in_sizes, int n_in,
                              void* d_out, int out_size, void* d_ws, size_t ws_size,
                              hipStream_t stream) {
  (void)in_sizes; (void)n_in; (void)out_size;
  const int*   x       = (const int*)  d_in[0];
  const float* emb     = (const float*)d_in[1];
  const float* W_ih    = (const float*)d_in[2];
  const float* W_hh    = (const float*)d_in[3];
  const float* b_ih    = (const float*)d_in[4];
  const float* b_hh    = (const float*)d_in[5];
  const float* key_W   = (const float*)d_in[6];
  const float* key_b   = (const float*)d_in[7];
  const float* beta_W  = (const float*)d_in[8];
  const float* beta_b  = (const float*)d_in[9];
  const float* gate_W  = (const float*)d_in[10];
  const float* gate_b  = (const float*)d_in[11];
  const float* shift_W = (const float*)d_in[12];
  const float* shift_b = (const float*)d_in[13];
  const float* gamma_W = (const float*)d_in[14];
  const float* gamma_b = (const float*)d_in[15];
  const float* erase_W = (const float*)d_in[16];
  const float* erase_b = (const float*)d_in[17];
  const float* add_W   = (const float*)d_in[18];
  const float* add_b   = (const float*)d_in[19];
  const float* out_W   = (const float*)d_in[20];
  const float* out_b   = (const float*)d_in[21];
  const float* mem_init= (const float*)d_in[22];
  float* ws  = (float*)d_ws;
  float* out = (float*)d_out;

  int prep_blocks = (PREP_ITEMS + 255) / 256;
  ntm_prep<<<prep_blocks, 256, 0, stream>>>(W_ih, W_hh, b_ih, b_hh, key_W, key_b,
      beta_W, beta_b, gate_W, gate_b, shift_W, shift_b, gamma_W, gamma_b,
      erase_W, erase_b, add_W, add_b, out_W, ws);

  bool split = (ws_size >= (size_t)WS_SPLIT_BYTES);
  if (split) {
    hipFuncSetAttribute((const void*)ntm_main<1>, hipFuncAttributeMaxDynamicSharedMemorySize,
                        SMEM_BYTES);
    ntm_main<1><<<NB, 1024, SMEM_BYTES, stream>>>(x, emb, out_b, mem_init, ws, out);
    ntm_logits<<<(NB * NS) / 16, 512, 0, stream>>>(ws, out_b, out);
  } else {
    hipFuncSetAttribute((const void*)ntm_main<0>, hipFuncAttributeMaxDynamicSharedMemorySize,
                        SMEM_BYTES);
    ntm_main<0><<<NB, 1024, SMEM_BYTES, stream>>>(x, emb, out_b, mem_init, ws, out);
  }
}